// Round 1
// baseline (8547.039 us; speedup 1.0000x reference)
//
#include <hip/hip_runtime.h>

#define B_ 16
#define N_ 8192
#define G_ 256
#define K_ 64
#define D_ 256
#define HID_ 1024
#define EPS_ 1e-5f

__device__ __forceinline__ float bf16_to_f32(unsigned short u){
  unsigned int v = ((unsigned int)u) << 16;
  return __uint_as_float(v);
}
__device__ __forceinline__ unsigned short f32_to_bf16(float f){
  unsigned int u = __float_as_uint(f);
  unsigned int r = (u + 0x7FFFu + ((u >> 16) & 1u)) >> 16;
  return (unsigned short)r;
}
__device__ __forceinline__ float gelu_exact(float v){
  return 0.5f * v * (1.0f + erff(v * 0.70710678118654752440f));
}

// ---------------- fold BN into enc_w1/enc_w3 ----------------
__global__ void fold_kernel(const float* __restrict__ w1, const float* __restrict__ b1,
    const float* __restrict__ g1, const float* __restrict__ bb1,
    const float* __restrict__ w3, const float* __restrict__ b3,
    const float* __restrict__ g2, const float* __restrict__ bb2,
    float* __restrict__ w1f, float* __restrict__ b1f,
    float* __restrict__ w3f, float* __restrict__ b3f)
{
  int i = blockIdx.x * 256 + threadIdx.x;
  const float S = 0.99999500003749968f; // 1/sqrt(1+1e-5)
  if (i < 384) w1f[i] = w1[i] * g1[i & 127] * S;
  if (i < 128) b1f[i] = b1[i] * g1[i] * S + bb1[i];
  if (i < 262144) w3f[i] = w3[i] * g2[i & 511] * S;
  if (i < 512) b3f[i] = b3[i] * g2[i] * S + bb2[i];
}

// ---------------- FPS: one block per batch ----------------
__global__ __launch_bounds__(1024) void fps_kernel(const float* __restrict__ x, float* __restrict__ centers)
{
  int b = blockIdx.x;
  const float* xb = x + (size_t)b * N_ * 3;
  int tid = threadIdx.x;
  float px[8], py[8], pz[8], dist[8];
#pragma unroll
  for (int j = 0; j < 8; j++){
    int p = tid + j * 1024;
    px[j] = xb[p*3+0]; py[j] = xb[p*3+1]; pz[j] = xb[p*3+2];
    dist[j] = 1e10f;
  }
  __shared__ unsigned long long wred[16];
  __shared__ float sCen[3];
  if (tid == 0){ sCen[0] = xb[0]; sCen[1] = xb[1]; sCen[2] = xb[2]; }
  __syncthreads();
  for (int i = 0; i < G_; i++){
    float cx = sCen[0], cy = sCen[1], cz = sCen[2];
    if (tid < 3) centers[((size_t)b * G_ + i) * 3 + tid] = sCen[tid];
    unsigned long long best = 0ull;
#pragma unroll
    for (int j = 0; j < 8; j++){
      // exact: d = (dx*dx + dy*dy) + dz*dz, no FMA contraction
      float dx = __fadd_rn(px[j], -cx);
      float dy = __fadd_rn(py[j], -cy);
      float dz = __fadd_rn(pz[j], -cz);
      float d  = __fadd_rn(__fadd_rn(__fmul_rn(dx,dx), __fmul_rn(dy,dy)), __fmul_rn(dz,dz));
      float dm = fminf(dist[j], d);
      dist[j] = dm;
      unsigned int pp = (unsigned int)(tid + j * 1024);
      unsigned long long key = (((unsigned long long)__float_as_uint(dm)) << 32) | (unsigned long long)(~pp);
      best = (key > best) ? key : best;
    }
#pragma unroll
    for (int o = 32; o; o >>= 1){
      unsigned long long t = __shfl_down(best, o);
      best = (t > best) ? t : best;
    }
    if ((tid & 63) == 0) wred[tid >> 6] = best;
    __syncthreads();
    unsigned long long m = wred[0];
#pragma unroll
    for (int w = 1; w < 16; w++){ unsigned long long t = wred[w]; m = (t > m) ? t : m; }
    int far = (int)(~(unsigned int)(m & 0xFFFFFFFFull));
    if (i + 1 < G_){
      if (tid == (far & 1023)){
        int jj = far >> 10;
        float fx=0.f, fy=0.f, fz=0.f;
#pragma unroll
        for (int j = 0; j < 8; j++) if (j == jj){ fx = px[j]; fy = py[j]; fz = pz[j]; }
        sCen[0] = fx; sCen[1] = fy; sCen[2] = fz;
      }
      __syncthreads();
    }
  }
}

// ---------------- KNN: one block per (b,g) ----------------
__global__ __launch_bounds__(256) void knn_kernel(const float* __restrict__ x, const float* __restrict__ centers,
                                                  int* __restrict__ knn_idx, float* __restrict__ neigh)
{
  int blk = blockIdx.x, b = blk >> 8;
  const float* xb = x + (size_t)b * N_ * 3;
  const float* cc = centers + (size_t)blk * 3;
  int tid = threadIdx.x;
  float c0 = cc[0], c1 = cc[1], c2v = cc[2];
  float c2s = __fadd_rn(__fadd_rn(__fmul_rn(c0,c0), __fmul_rn(c1,c1)), __fmul_rn(c2v,c2v));
  float d[32];
#pragma unroll
  for (int j = 0; j < 32; j++){
    int p = tid + j * 256;
    float x0 = xb[p*3+0], x1 = xb[p*3+1], x2 = xb[p*3+2];
    float xs = __fadd_rn(__fadd_rn(__fmul_rn(x0,x0), __fmul_rn(x1,x1)), __fmul_rn(x2,x2));
    float dt = __fadd_rn(__fadd_rn(__fmul_rn(c0,x0), __fmul_rn(c1,x1)), __fmul_rn(c2v,x2));
    d[j] = __fadd_rn(__fadd_rn(c2s, xs), -__fmul_rn(2.0f, dt));
  }
  const float FINF = __int_as_float(0x7F800000);
  float lmin = FINF; unsigned int lp = 0xFFFFFFFFu;
#pragma unroll
  for (int j = 0; j < 32; j++){ if (d[j] < lmin){ lmin = d[j]; lp = (unsigned int)(tid + j*256); } }
  __shared__ unsigned long long wred[2][4];
  for (int r = 0; r < K_; r++){
    unsigned int u = __float_as_uint(lmin);
    u = (u & 0x80000000u) ? ~u : (u | 0x80000000u);
    unsigned long long key = (((unsigned long long)u) << 32) | (unsigned long long)lp;
#pragma unroll
    for (int o = 32; o; o >>= 1){
      unsigned long long t = __shfl_down(key, o);
      key = (t < key) ? t : key;
    }
    int cur = r & 1;
    if ((tid & 63) == 0) wred[cur][tid >> 6] = key;
    __syncthreads();
    unsigned long long m = wred[cur][0];
#pragma unroll
    for (int w = 1; w < 4; w++){ unsigned long long t = wred[cur][w]; m = (t < m) ? t : m; }
    unsigned int p = (unsigned int)(m & 0xFFFFFFFFull);
    if (tid == (p & 255u)){
      knn_idx[(size_t)blk * K_ + r] = (int)p;
      float* np_ = neigh + ((size_t)blk * K_ + r) * 3;
      np_[0] = __fadd_rn(xb[p*3+0], -c0);
      np_[1] = __fadd_rn(xb[p*3+1], -c1);
      np_[2] = __fadd_rn(xb[p*3+2], -c2v);
      lmin = FINF; lp = 0xFFFFFFFFu;
#pragma unroll
      for (int j = 0; j < 32; j++){
        if ((unsigned int)(tid + j*256) == p) d[j] = FINF;
        if (d[j] < lmin){ lmin = d[j]; lp = (unsigned int)(tid + j*256); }
      }
    }
  }
}

// ---------------- fused group encoder: one block per (b,g) ----------------
__global__ __launch_bounds__(256) void encoder_kernel(
    const float* __restrict__ neigh, const float* __restrict__ w1f, const float* __restrict__ b1f,
    const float* __restrict__ w2, const float* __restrict__ b2,
    const float* __restrict__ w3f, const float* __restrict__ b3f,
    const float* __restrict__ w4, const float* __restrict__ b4,
    float* __restrict__ tokens)
{
  __shared__ __align__(16) unsigned short sH2[64 * 258]; // h2 (64x256) in bf16
  __shared__ float sH3[64 * 65];                          // h3 col-tile (64x64)
  __shared__ float sGmax[256];
  __shared__ float sNeigh[64][4];
  __shared__ float sPartA[4 * 64];
  __shared__ float sW1[512];
  int tid = threadIdx.x;
  size_t gid = blockIdx.x;
  const float* nb = neigh + gid * 192;
  if (tid < 192) sNeigh[tid / 3][tid % 3] = nb[tid];
  sW1[tid] = (tid < 384) ? w1f[tid] : b1f[tid - 384];
  { int t2 = tid + 256; sW1[t2] = (t2 < 384) ? w1f[t2] : b1f[t2 - 384]; }
  __syncthreads();

  int tr = tid >> 4, tc = tid & 15; // rows 4tr..4tr+3, col base 4tc

  // ---- phase 2: h2 = h1 @ w2 + b2, h1 recomputed from neigh ----
  float n0[4], n1[4], n2[4];
#pragma unroll
  for (int i = 0; i < 4; i++){
    n0[i] = sNeigh[4*tr+i][0]; n1[i] = sNeigh[4*tr+i][1]; n2[i] = sNeigh[4*tr+i][2];
  }
  float acc[4][16];
#pragma unroll
  for (int i = 0; i < 4; i++)
#pragma unroll
    for (int j = 0; j < 16; j++) acc[i][j] = 0.0f;
#pragma unroll 4
  for (int k = 0; k < 128; k++){
    float wa = sW1[k], wb = sW1[128+k], wc = sW1[256+k], bb = sW1[384+k];
    float a[4];
#pragma unroll
    for (int i = 0; i < 4; i++)
      a[i] = fmaxf(fmaf(n2[i], wc, fmaf(n1[i], wb, fmaf(n0[i], wa, bb))), 0.0f);
#pragma unroll
    for (int cb = 0; cb < 4; cb++){
      const float4 w = *(const float4*)(w2 + (size_t)k * 256 + cb * 64 + tc * 4);
#pragma unroll
      for (int i = 0; i < 4; i++){
        acc[i][cb*4+0] = fmaf(a[i], w.x, acc[i][cb*4+0]);
        acc[i][cb*4+1] = fmaf(a[i], w.y, acc[i][cb*4+1]);
        acc[i][cb*4+2] = fmaf(a[i], w.z, acc[i][cb*4+2]);
        acc[i][cb*4+3] = fmaf(a[i], w.w, acc[i][cb*4+3]);
      }
    }
  }
#pragma unroll
  for (int cb = 0; cb < 4; cb++)
#pragma unroll
    for (int j2 = 0; j2 < 4; j2++){
      int col = cb * 64 + tc * 4 + j2;
      float bias = b2[col];
#pragma unroll
      for (int i = 0; i < 4; i++)
        sH2[(4*tr+i)*258 + col] = f32_to_bf16(acc[i][cb*4+j2] + bias);
    }
  __syncthreads();

  // ---- phase 3: gmax = colmax(h2) ----
  {
    float mx = __int_as_float(0xFF800000);
    for (int r2 = 0; r2 < 64; r2++) mx = fmaxf(mx, bf16_to_f32(sH2[r2*258 + tid]));
    sGmax[tid] = mx;
  }
  __syncthreads();

  // ---- phase 4: h3 col-tiles (ext = [gmax | h2]) -> relu/bn -> h4 accum ----
  float h4[4][16];
#pragma unroll
  for (int i = 0; i < 4; i++)
#pragma unroll
    for (int j = 0; j < 16; j++) h4[i][j] = 0.0f;

  for (int cb4 = 0; cb4 < 8; cb4++){
    { // partA: gmax part of h3, computed once per column (row-independent)
      int c = tid & 63, kq = tid >> 6;
      const float* wcol = w3f + (size_t)(kq * 64) * 512 + cb4 * 64 + c;
      float s = 0.0f;
#pragma unroll 4
      for (int k = 0; k < 64; k++) s = fmaf(sGmax[kq*64 + k], wcol[(size_t)k * 512], s);
      sPartA[kq * 64 + c] = s;
    }
    __syncthreads();
    float hacc[4][4];
#pragma unroll
    for (int j2 = 0; j2 < 4; j2++){
      int c = tc * 4 + j2;
      float pa = ((sPartA[c] + sPartA[64+c]) + sPartA[128+c]) + sPartA[192+c];
#pragma unroll
      for (int i = 0; i < 4; i++) hacc[i][j2] = pa;
    }
#pragma unroll 4
    for (int k = 0; k < 256; k++){
      float a[4];
#pragma unroll
      for (int i = 0; i < 4; i++) a[i] = bf16_to_f32(sH2[(4*tr+i)*258 + k]);
      const float4 w = *(const float4*)(w3f + (size_t)(256 + k) * 512 + cb4 * 64 + tc * 4);
#pragma unroll
      for (int i = 0; i < 4; i++){
        hacc[i][0] = fmaf(a[i], w.x, hacc[i][0]);
        hacc[i][1] = fmaf(a[i], w.y, hacc[i][1]);
        hacc[i][2] = fmaf(a[i], w.z, hacc[i][2]);
        hacc[i][3] = fmaf(a[i], w.w, hacc[i][3]);
      }
    }
#pragma unroll
    for (int j2 = 0; j2 < 4; j2++){
      int c = cb4 * 64 + tc * 4 + j2;
      float bias = b3f[c];
#pragma unroll
      for (int i = 0; i < 4; i++)
        sH3[(4*tr+i)*65 + tc*4 + j2] = fmaxf(hacc[i][j2] + bias, 0.0f);
    }
    __syncthreads();
#pragma unroll 4
    for (int k = 0; k < 64; k++){
      float a[4];
#pragma unroll
      for (int i = 0; i < 4; i++) a[i] = sH3[(4*tr+i)*65 + k];
      const float* w4row = w4 + (size_t)(cb4 * 64 + k) * 256;
#pragma unroll
      for (int cb = 0; cb < 4; cb++){
        const float4 w = *(const float4*)(w4row + cb * 64 + tc * 4);
#pragma unroll
        for (int i = 0; i < 4; i++){
          h4[i][cb*4+0] = fmaf(a[i], w.x, h4[i][cb*4+0]);
          h4[i][cb*4+1] = fmaf(a[i], w.y, h4[i][cb*4+1]);
          h4[i][cb*4+2] = fmaf(a[i], w.z, h4[i][cb*4+2]);
          h4[i][cb*4+3] = fmaf(a[i], w.w, h4[i][cb*4+3]);
        }
      }
    }
    __syncthreads();
  }

  // ---- phase 5: tokens = colmax(h4) + b4 ----
  float* cmax = reinterpret_cast<float*>(sH2); // reuse (16 KB needed, 33 KB available)
#pragma unroll
  for (int cb = 0; cb < 4; cb++)
#pragma unroll
    for (int j2 = 0; j2 < 4; j2++){
      float mx = fmaxf(fmaxf(h4[0][cb*4+j2], h4[1][cb*4+j2]), fmaxf(h4[2][cb*4+j2], h4[3][cb*4+j2]));
      cmax[tr * 256 + cb * 64 + tc * 4 + j2] = mx;
    }
  __syncthreads();
  {
    float mx = cmax[tid];
#pragma unroll
    for (int i = 1; i < 16; i++) mx = fmaxf(mx, cmax[i * 256 + tid]);
    tokens[gid * 256 + tid] = mx + b4[tid];
  }
}

// ---------------- pos embed + assemble xt/pt ----------------
__global__ __launch_bounds__(128) void pos_token_kernel(
    const float* __restrict__ centers, const float* __restrict__ tokens,
    const float* __restrict__ cls_token, const float* __restrict__ cls_pos,
    const float* __restrict__ pw1, const float* __restrict__ pb1,
    const float* __restrict__ pw2, const float* __restrict__ pb2,
    float* __restrict__ xt, float* __restrict__ pt)
{
  int row = blockIdx.x;
  int b = row / 257, n = row - b * 257;
  int tid = threadIdx.x;
  size_t ro = (size_t)row * 256;
  if (n == 0){
    xt[ro + tid] = cls_token[tid]; xt[ro + 128 + tid] = cls_token[128 + tid];
    pt[ro + tid] = cls_pos[tid];   pt[ro + 128 + tid] = cls_pos[128 + tid];
    return;
  }
  int g = n - 1;
  const float* c = centers + ((size_t)b * 256 + g) * 3;
  __shared__ float hS[128];
  float h = fmaf(c[2], pw1[256 + tid], fmaf(c[1], pw1[128 + tid], fmaf(c[0], pw1[tid], pb1[tid])));
  hS[tid] = gelu_exact(h);
  __syncthreads();
  const float* tok = tokens + ((size_t)b * 256 + g) * 256;
#pragma unroll
  for (int half = 0; half < 2; half++){
    int j = tid + half * 128;
    float s = pb2[j];
#pragma unroll 4
    for (int k = 0; k < 128; k++) s = fmaf(hS[k], pw2[(size_t)k * 256 + j], s);
    pt[ro + j] = s;
    xt[ro + j] = tok[j];
  }
}

// ---------------- add + layernorm (row of 256) ----------------
__global__ __launch_bounds__(256) void add_ln_kernel(const float* __restrict__ A, const float* __restrict__ Badd,
    float* __restrict__ xi_out, float* __restrict__ ln_out,
    const float* __restrict__ g, const float* __restrict__ be)
{
  __shared__ float red[4];
  int row = blockIdx.x, c = threadIdx.x;
  size_t off = (size_t)row * 256 + c;
  float v = A[off];
  if (Badd) v += Badd[off];
  if (xi_out) xi_out[off] = v;
  float s = v;
#pragma unroll
  for (int o = 32; o; o >>= 1) s += __shfl_down(s, o);
  if ((threadIdx.x & 63) == 0) red[threadIdx.x >> 6] = s;
  __syncthreads();
  float m = (red[0] + red[1] + red[2] + red[3]) * (1.0f / 256.0f);
  __syncthreads();
  float d = v - m;
  float s2 = d * d;
#pragma unroll
  for (int o = 32; o; o >>= 1) s2 += __shfl_down(s2, o);
  if ((threadIdx.x & 63) == 0) red[threadIdx.x >> 6] = s2;
  __syncthreads();
  float var = (red[0] + red[1] + red[2] + red[3]) * (1.0f / 256.0f);
  ln_out[off] = d / sqrtf(var + EPS_) * g[c] + be[c];
}

// ---------------- generic tiled f32 GEMM (64x64 tile, 4x4/thread) ----------------
// C = [res +] act(A@W + bias)
template<int ACT>
__global__ __launch_bounds__(256) void gemm_kernel(
    const float* __restrict__ A, const float* __restrict__ W, const float* __restrict__ bias,
    const float* __restrict__ res, float* __restrict__ C, int M, int K, int N)
{
  __shared__ float As[16][68];
  __shared__ float Ws[16][68];
  int row0 = blockIdx.x * 64, col0 = blockIdx.y * 64;
  int tid = threadIdx.x;
  int tr = tid >> 4, tc = tid & 15;
  int ar = tid >> 2, ac = (tid & 3) * 4;
  int wr = tid >> 4, wc = (tid & 15) * 4;
  float acc[4][4];
#pragma unroll
  for (int i = 0; i < 4; i++)
#pragma unroll
    for (int j = 0; j < 4; j++) acc[i][j] = 0.0f;
  for (int k0 = 0; k0 < K; k0 += 16){
    float4 av = make_float4(0.f, 0.f, 0.f, 0.f);
    int arow = row0 + ar;
    if (arow < M) av = *(const float4*)(A + (size_t)arow * K + k0 + ac);
    As[ac+0][ar] = av.x; As[ac+1][ar] = av.y; As[ac+2][ar] = av.z; As[ac+3][ar] = av.w;
    *(float4*)(&Ws[wr][wc]) = *(const float4*)(W + (size_t)(k0 + wr) * N + col0 + wc);
    __syncthreads();
#pragma unroll
    for (int kk = 0; kk < 16; kk++){
      float a0 = As[kk][tr*4+0], a1 = As[kk][tr*4+1], a2 = As[kk][tr*4+2], a3 = As[kk][tr*4+3];
      float4 bv = *(float4*)(&Ws[kk][tc*4]);
      acc[0][0]=fmaf(a0,bv.x,acc[0][0]); acc[0][1]=fmaf(a0,bv.y,acc[0][1]); acc[0][2]=fmaf(a0,bv.z,acc[0][2]); acc[0][3]=fmaf(a0,bv.w,acc[0][3]);
      acc[1][0]=fmaf(a1,bv.x,acc[1][0]); acc[1][1]=fmaf(a1,bv.y,acc[1][1]); acc[1][2]=fmaf(a1,bv.z,acc[1][2]); acc[1][3]=fmaf(a1,bv.w,acc[1][3]);
      acc[2][0]=fmaf(a2,bv.x,acc[2][0]); acc[2][1]=fmaf(a2,bv.y,acc[2][1]); acc[2][2]=fmaf(a2,bv.z,acc[2][2]); acc[2][3]=fmaf(a2,bv.w,acc[2][3]);
      acc[3][0]=fmaf(a3,bv.x,acc[3][0]); acc[3][1]=fmaf(a3,bv.y,acc[3][1]); acc[3][2]=fmaf(a3,bv.z,acc[3][2]); acc[3][3]=fmaf(a3,bv.w,acc[3][3]);
    }
    __syncthreads();
  }
#pragma unroll
  for (int i = 0; i < 4; i++){
    int r = row0 + tr * 4 + i;
    if (r < M){
#pragma unroll
      for (int j = 0; j < 4; j++){
        int c = col0 + tc * 4 + j;
        float v = acc[i][j];
        if (bias) v += bias[c];
        if (ACT == 1) v = gelu_exact(v);
        if (res) v += res[(size_t)r * N + c];
        C[(size_t)r * N + c] = v;
      }
    }
  }
}

// ---------------- attention: one block per (b,h), flash-style ----------------
__global__ __launch_bounds__(320) void attn_kernel(const float* __restrict__ qkv, float* __restrict__ obuf)
{
  int bh = blockIdx.x;
  int b = bh >> 3, h = bh & 7;
  __shared__ float kS[128][33];
  __shared__ float vS[128][33];
  const float* qb = qkv + (size_t)b * 257 * 768;
  int tid = threadIdx.x;
  float q[32], o[32];
  float mrun = -3.4e38f, l = 0.0f;
  if (tid < 257){
    const float* qr = qb + (size_t)tid * 768 + h * 32;
#pragma unroll
    for (int j = 0; j < 32; j++){ q[j] = qr[j]; o[j] = 0.0f; }
  }
  const float scale = 0.17677669529663687f; // 32^-0.5
  for (int m0 = 0; m0 < 257; m0 += 128){
    int cnt = min(128, 257 - m0);
    for (int e = tid; e < cnt * 32; e += 320){
      int mm = e >> 5, j = e & 31;
      const float* rowp = qb + (size_t)(m0 + mm) * 768 + h * 32;
      kS[mm][j] = rowp[256 + j];
      vS[mm][j] = rowp[512 + j];
    }
    __syncthreads();
    if (tid < 257){
      for (int mm = 0; mm < cnt; mm++){
        float s = 0.0f;
#pragma unroll
        for (int j = 0; j < 32; j++) s = fmaf(q[j], kS[mm][j], s);
        s *= scale;
        float nm = fmaxf(mrun, s);
        float alpha = expf(mrun - nm);
        float p = expf(s - nm);
        l = fmaf(l, alpha, p);
#pragma unroll
        for (int j = 0; j < 32; j++) o[j] = fmaf(p, vS[mm][j], o[j] * alpha);
        mrun = nm;
      }
    }
    __syncthreads();
  }
  if (tid < 257){
    float inv = 1.0f / l;
    float* orow = obuf + (size_t)(b * 257 + tid) * 256 + h * 32;
#pragma unroll
    for (int j = 0; j < 32; j++) orow[j] = o[j] * inv;
  }
}

// ---------------- head MLP + scatter: one block per (b,g) ----------------
__global__ __launch_bounds__(256) void head_kernel(
    const float* __restrict__ gfeat, const float* __restrict__ neigh, const int* __restrict__ knn_idx,
    const float* __restrict__ w1, const float* __restrict__ b1,
    const float* __restrict__ w2, const float* __restrict__ b2,
    float* __restrict__ sums, float* __restrict__ cnts)
{
  int blk = blockIdx.x, b = blk >> 8, g = blk & 255;
  __shared__ float xS[256];
  __shared__ float nS[192];
  int tid = threadIdx.x;
  xS[tid] = gfeat[((size_t)b * 257 + 1 + g) * 256 + tid];
  if (tid < 192) nS[tid] = neigh[(size_t)blk * 192 + tid];
  __syncthreads();
  int r = tid >> 2, q = tid & 3;
  float hacc[32];
#pragma unroll
  for (int j = 0; j < 32; j++) hacc[j] = b1[q * 32 + j];
#pragma unroll 2
  for (int k = 0; k < 256; k++){
    float xk = xS[k];
    const float* wrow = w1 + (size_t)k * 128 + q * 32;
#pragma unroll
    for (int j = 0; j < 32; j += 4){
      float4 w = *(const float4*)(wrow + j);
      hacc[j+0] = fmaf(xk, w.x, hacc[j+0]);
      hacc[j+1] = fmaf(xk, w.y, hacc[j+1]);
      hacc[j+2] = fmaf(xk, w.z, hacc[j+2]);
      hacc[j+3] = fmaf(xk, w.w, hacc[j+3]);
    }
  }
#pragma unroll
  for (int k = 0; k < 3; k++){
    float xk = nS[r * 3 + k];
    const float* wrow = w1 + (size_t)(256 + k) * 128 + q * 32;
#pragma unroll
    for (int j = 0; j < 32; j += 4){
      float4 w = *(const float4*)(wrow + j);
      hacc[j+0] = fmaf(xk, w.x, hacc[j+0]);
      hacc[j+1] = fmaf(xk, w.y, hacc[j+1]);
      hacc[j+2] = fmaf(xk, w.z, hacc[j+2]);
      hacc[j+3] = fmaf(xk, w.w, hacc[j+3]);
    }
  }
  float s = 0.0f;
#pragma unroll
  for (int j = 0; j < 32; j++) s = fmaf(fmaxf(hacc[j], 0.0f), w2[q * 32 + j], s);
  s += __shfl_xor(s, 1);
  s += __shfl_xor(s, 2);
  if (q == 0){
    float lg = s + b2[0];
    int p = knn_idx[(size_t)blk * K_ + r];
    atomicAdd(&sums[(size_t)b * N_ + p], lg);
    atomicAdd(&cnts[(size_t)b * N_ + p], 1.0f);
  }
}

__global__ void finalize_kernel(const float* __restrict__ sums, const float* __restrict__ cnts, float* __restrict__ out)
{
  int i = blockIdx.x * 256 + threadIdx.x;
  out[i] = sums[i] / fmaxf(cnts[i], 1.0f);
}

extern "C" void kernel_launch(void* const* d_in, const int* in_sizes, int n_in,
                              void* d_out, int out_size, void* d_ws, size_t ws_size,
                              hipStream_t stream)
{
  (void)in_sizes; (void)n_in; (void)out_size; (void)ws_size;
  const float* x        = (const float*)d_in[0];
  const float* enc_w1   = (const float*)d_in[1];
  const float* enc_b1   = (const float*)d_in[2];
  const float* enc_bn1g = (const float*)d_in[3];
  const float* enc_bn1b = (const float*)d_in[4];
  const float* enc_w2   = (const float*)d_in[5];
  const float* enc_b2   = (const float*)d_in[6];
  const float* enc_w3   = (const float*)d_in[7];
  const float* enc_b3   = (const float*)d_in[8];
  const float* enc_bn2g = (const float*)d_in[9];
  const float* enc_bn2b = (const float*)d_in[10];
  const float* enc_w4   = (const float*)d_in[11];
  const float* enc_b4   = (const float*)d_in[12];
  const float* cls_tok  = (const float*)d_in[13];
  const float* cls_pos  = (const float*)d_in[14];
  const float* pos_w1   = (const float*)d_in[15];
  const float* pos_b1   = (const float*)d_in[16];
  const float* pos_w2   = (const float*)d_in[17];
  const float* pos_b2   = (const float*)d_in[18];
  const float* ln1_g    = (const float*)d_in[19];
  const float* ln1_b    = (const float*)d_in[20];
  const float* qkv_w    = (const float*)d_in[21];
  const float* proj_w   = (const float*)d_in[22];
  const float* proj_b   = (const float*)d_in[23];
  const float* ln2_g    = (const float*)d_in[24];
  const float* ln2_b    = (const float*)d_in[25];
  const float* fc1_w    = (const float*)d_in[26];
  const float* fc1_b    = (const float*)d_in[27];
  const float* fc2_w    = (const float*)d_in[28];
  const float* fc2_b    = (const float*)d_in[29];
  const float* norm_g   = (const float*)d_in[30];
  const float* norm_b   = (const float*)d_in[31];
  const float* head_w1  = (const float*)d_in[32];
  const float* head_b1  = (const float*)d_in[33];
  const float* head_w2  = (const float*)d_in[34];
  const float* head_b2  = (const float*)d_in[35];

  float* ws = (float*)d_ws;
  size_t off = 0;
  auto alloc = [&](size_t n)->float*{ float* p = ws + off; off += (n + 63) & ~(size_t)63; return p; };

  float* centers = alloc((size_t)B_ * G_ * 3);
  float* w1f     = alloc(384);
  float* b1f     = alloc(128);
  float* w3f     = alloc(512 * 512);
  float* b3f     = alloc(512);
  float* tokens  = alloc((size_t)B_ * G_ * D_);
  float* neigh   = alloc((size_t)B_ * G_ * K_ * 3);
  int*   knn_idx = (int*)alloc((size_t)B_ * G_ * K_);
  float* pt      = alloc((size_t)B_ * 257 * D_);
  float* xt      = alloc((size_t)B_ * 257 * D_);
  float* xi      = alloc((size_t)B_ * 257 * D_);
  float* lnbuf   = alloc((size_t)B_ * 257 * D_);
  float* obuf    = alloc((size_t)B_ * 257 * D_);
  float* bigbuf  = alloc((size_t)B_ * 257 * HID_); // shared: qkv (B*257*768) then fc1-out (B*257*1024)
  float* gfeat   = alloc((size_t)B_ * 257 * D_);
  float* sums    = alloc((size_t)B_ * N_);
  float* cnts    = alloc((size_t)B_ * N_);

  hipMemsetAsync(sums, 0, (size_t)2 * B_ * N_ * sizeof(float), stream); // sums+cnts contiguous

  fold_kernel<<<1024, 256, 0, stream>>>(enc_w1, enc_b1, enc_bn1g, enc_bn1b,
                                        enc_w3, enc_b3, enc_bn2g, enc_bn2b,
                                        w1f, b1f, w3f, b3f);
  fps_kernel<<<B_, 1024, 0, stream>>>(x, centers);
  knn_kernel<<<B_ * G_, 256, 0, stream>>>(x, centers, knn_idx, neigh);
  encoder_kernel<<<B_ * G_, 256, 0, stream>>>(neigh, w1f, b1f, enc_w2, enc_b2,
                                              w3f, b3f, enc_w4, enc_b4, tokens);
  pos_token_kernel<<<B_ * 257, 128, 0, stream>>>(centers, tokens, cls_tok, cls_pos,
                                                 pos_w1, pos_b1, pos_w2, pos_b2, xt, pt);
  const int M = B_ * 257; // 4112
  for (int l = 0; l < 4; l++){
    add_ln_kernel<<<M, 256, 0, stream>>>(xt, pt, xi, lnbuf, ln1_g + l*256, ln1_b + l*256);
    gemm_kernel<0><<<dim3(65, 12), 256, 0, stream>>>(lnbuf, qkv_w + (size_t)l*256*768, nullptr, nullptr, bigbuf, M, 256, 768);
    attn_kernel<<<B_ * 8, 320, 0, stream>>>(bigbuf, obuf);
    gemm_kernel<0><<<dim3(65, 4), 256, 0, stream>>>(obuf, proj_w + (size_t)l*256*256, proj_b + l*256, xi, xi, M, 256, 256);
    add_ln_kernel<<<M, 256, 0, stream>>>(xi, nullptr, nullptr, lnbuf, ln2_g + l*256, ln2_b + l*256);
    gemm_kernel<1><<<dim3(65, 16), 256, 0, stream>>>(lnbuf, fc1_w + (size_t)l*256*1024, fc1_b + l*1024, nullptr, bigbuf, M, 256, 1024);
    gemm_kernel<0><<<dim3(65, 4), 256, 0, stream>>>(bigbuf, fc2_w + (size_t)l*1024*256, fc2_b + l*256, xi, xt, M, 1024, 256);
  }
  add_ln_kernel<<<M, 256, 0, stream>>>(xt, nullptr, nullptr, gfeat, norm_g, norm_b);
  head_kernel<<<B_ * G_, 256, 0, stream>>>(gfeat, neigh, knn_idx, head_w1, head_b1, head_w2, head_b2, sums, cnts);
  finalize_kernel<<<(B_ * N_) / 256, 256, 0, stream>>>(sums, cnts, (float*)d_out);
}

// Round 2
// 2626.930 us; speedup vs baseline: 3.2536x; 3.2536x over previous
//
#include <hip/hip_runtime.h>

#define B_ 16
#define N_ 8192
#define G_ 256
#define K_ 64
#define D_ 256
#define HID_ 1024
#define EPS_ 1e-5f

typedef __attribute__((ext_vector_type(8))) short bf16x8;
typedef __attribute__((ext_vector_type(4))) float f32x4;

__device__ __forceinline__ float bf16_to_f32(unsigned short u){
  unsigned int v = ((unsigned int)u) << 16;
  return __uint_as_float(v);
}
__device__ __forceinline__ unsigned short f32_to_bf16(float f){
  unsigned int u = __float_as_uint(f);
  unsigned int r = (u + 0x7FFFu + ((u >> 16) & 1u)) >> 16;
  return (unsigned short)r;
}
__device__ __forceinline__ float gelu_exact(float v){
  return 0.5f * v * (1.0f + erff(v * 0.70710678118654752440f));
}

// ---------------- fold BN into enc_w1/enc_w3 ----------------
__global__ void fold_kernel(const float* __restrict__ w1, const float* __restrict__ b1,
    const float* __restrict__ g1, const float* __restrict__ bb1,
    const float* __restrict__ w3, const float* __restrict__ b3,
    const float* __restrict__ g2, const float* __restrict__ bb2,
    float* __restrict__ w1f, float* __restrict__ b1f,
    float* __restrict__ w3f, float* __restrict__ b3f)
{
  int i = blockIdx.x * 256 + threadIdx.x;
  const float S = 0.99999500003749968f; // 1/sqrt(1+1e-5)
  if (i < 384) w1f[i] = w1[i] * g1[i & 127] * S;
  if (i < 128) b1f[i] = b1[i] * g1[i] * S + bb1[i];
  if (i < 262144) w3f[i] = w3[i] * g2[i & 511] * S;
  if (i < 512) b3f[i] = b3[i] * g2[i] * S + bb2[i];
}

// ---- pack weights into MFMA B-fragment layout, hi/lo bf16 split ----
// B frag for 16x16x32: lane holds B[k = (lane>>4)*8 + j][n = lane&15], j=0..7
// packed[( (nt*KS + ks)*64 + lane)*8 + j]
__global__ void pack_w2_kernel(const float* __restrict__ w2, unsigned short* __restrict__ hi, unsigned short* __restrict__ lo){
  int f = blockIdx.x * 256 + threadIdx.x; // 32768 = 16nt * 4ks * 64 * 8
  int j = f & 7, lane = (f >> 3) & 63, ks = (f >> 9) & 3, nt = f >> 11;
  int k = ks * 32 + ((lane >> 4) & 3) * 8 + j, c = nt * 16 + (lane & 15);
  float v = w2[(size_t)k * 256 + c];
  unsigned short h = f32_to_bf16(v);
  hi[f] = h;
  lo[f] = f32_to_bf16(v - bf16_to_f32(h));
}
__global__ void pack_w3_kernel(const float* __restrict__ w3f, unsigned short* __restrict__ hi, unsigned short* __restrict__ lo){
  int f = blockIdx.x * 256 + threadIdx.x; // 131072 = 32nt * 8ks * 64 * 8 (bottom half rows 256..511)
  int j = f & 7, lane = (f >> 3) & 63, ks = (f >> 9) & 7, nt = f >> 12;
  int k = ks * 32 + ((lane >> 4) & 3) * 8 + j, c = nt * 16 + (lane & 15);
  float v = w3f[(size_t)(256 + k) * 512 + c];
  unsigned short h = f32_to_bf16(v);
  hi[f] = h;
  lo[f] = f32_to_bf16(v - bf16_to_f32(h));
}
__global__ void pack_w4_kernel(const float* __restrict__ w4, unsigned short* __restrict__ hi, unsigned short* __restrict__ lo){
  int f = blockIdx.x * 256 + threadIdx.x; // 131072 = 16nt * 16ks * 64 * 8
  int j = f & 7, lane = (f >> 3) & 63, ks = (f >> 9) & 15, nt = f >> 13;
  int k = ks * 32 + ((lane >> 4) & 3) * 8 + j, c = nt * 16 + (lane & 15);
  float v = w4[(size_t)k * 256 + c];
  unsigned short h = f32_to_bf16(v);
  hi[f] = h;
  lo[f] = f32_to_bf16(v - bf16_to_f32(h));
}

// ---------------- FPS: one block per batch ----------------
__global__ __launch_bounds__(1024) void fps_kernel(const float* __restrict__ x, float* __restrict__ centers)
{
  int b = blockIdx.x;
  const float* xb = x + (size_t)b * N_ * 3;
  int tid = threadIdx.x;
  float px[8], py[8], pz[8], dist[8];
#pragma unroll
  for (int j = 0; j < 8; j++){
    int p = tid + j * 1024;
    px[j] = xb[p*3+0]; py[j] = xb[p*3+1]; pz[j] = xb[p*3+2];
    dist[j] = 1e10f;
  }
  __shared__ unsigned long long wred[16];
  __shared__ float sCen[3];
  if (tid == 0){ sCen[0] = xb[0]; sCen[1] = xb[1]; sCen[2] = xb[2]; }
  __syncthreads();
  for (int i = 0; i < G_; i++){
    float cx = sCen[0], cy = sCen[1], cz = sCen[2];
    if (tid < 3) centers[((size_t)b * G_ + i) * 3 + tid] = sCen[tid];
    unsigned long long best = 0ull;
#pragma unroll
    for (int j = 0; j < 8; j++){
      float dx = __fadd_rn(px[j], -cx);
      float dy = __fadd_rn(py[j], -cy);
      float dz = __fadd_rn(pz[j], -cz);
      float d  = __fadd_rn(__fadd_rn(__fmul_rn(dx,dx), __fmul_rn(dy,dy)), __fmul_rn(dz,dz));
      float dm = fminf(dist[j], d);
      dist[j] = dm;
      unsigned int pp = (unsigned int)(tid + j * 1024);
      unsigned long long key = (((unsigned long long)__float_as_uint(dm)) << 32) | (unsigned long long)(~pp);
      best = (key > best) ? key : best;
    }
#pragma unroll
    for (int o = 32; o; o >>= 1){
      unsigned long long t = __shfl_down(best, o);
      best = (t > best) ? t : best;
    }
    if ((tid & 63) == 0) wred[tid >> 6] = best;
    __syncthreads();
    unsigned long long m = wred[0];
#pragma unroll
    for (int w = 1; w < 16; w++){ unsigned long long t = wred[w]; m = (t > m) ? t : m; }
    int far = (int)(~(unsigned int)(m & 0xFFFFFFFFull));
    if (i + 1 < G_){
      if (tid == (far & 1023)){
        int jj = far >> 10;
        float fx=0.f, fy=0.f, fz=0.f;
#pragma unroll
        for (int j = 0; j < 8; j++) if (j == jj){ fx = px[j]; fy = py[j]; fz = pz[j]; }
        sCen[0] = fx; sCen[1] = fy; sCen[2] = fz;
      }
      __syncthreads();
    }
  }
}

// ---------------- KNN: one block per (b,g) ----------------
__global__ __launch_bounds__(256) void knn_kernel(const float* __restrict__ x, const float* __restrict__ centers,
                                                  int* __restrict__ knn_idx, float* __restrict__ neigh)
{
  int blk = blockIdx.x, b = blk >> 8;
  const float* xb = x + (size_t)b * N_ * 3;
  const float* cc = centers + (size_t)blk * 3;
  int tid = threadIdx.x;
  float c0 = cc[0], c1 = cc[1], c2v = cc[2];
  float c2s = __fadd_rn(__fadd_rn(__fmul_rn(c0,c0), __fmul_rn(c1,c1)), __fmul_rn(c2v,c2v));
  float d[32];
#pragma unroll
  for (int j = 0; j < 32; j++){
    int p = tid + j * 256;
    float x0 = xb[p*3+0], x1 = xb[p*3+1], x2 = xb[p*3+2];
    float xs = __fadd_rn(__fadd_rn(__fmul_rn(x0,x0), __fmul_rn(x1,x1)), __fmul_rn(x2,x2));
    float dt = __fadd_rn(__fadd_rn(__fmul_rn(c0,x0), __fmul_rn(c1,x1)), __fmul_rn(c2v,x2));
    d[j] = __fadd_rn(__fadd_rn(c2s, xs), -__fmul_rn(2.0f, dt));
  }
  const float FINF = __int_as_float(0x7F800000);
  float lmin = FINF; unsigned int lp = 0xFFFFFFFFu;
#pragma unroll
  for (int j = 0; j < 32; j++){ if (d[j] < lmin){ lmin = d[j]; lp = (unsigned int)(tid + j*256); } }
  __shared__ unsigned long long wred[2][4];
  for (int r = 0; r < K_; r++){
    unsigned int u = __float_as_uint(lmin);
    u = (u & 0x80000000u) ? ~u : (u | 0x80000000u);
    unsigned long long key = (((unsigned long long)u) << 32) | (unsigned long long)lp;
#pragma unroll
    for (int o = 32; o; o >>= 1){
      unsigned long long t = __shfl_down(key, o);
      key = (t < key) ? t : key;
    }
    int cur = r & 1;
    if ((tid & 63) == 0) wred[cur][tid >> 6] = key;
    __syncthreads();
    unsigned long long m = wred[cur][0];
#pragma unroll
    for (int w = 1; w < 4; w++){ unsigned long long t = wred[cur][w]; m = (t < m) ? t : m; }
    unsigned int p = (unsigned int)(m & 0xFFFFFFFFull);
    if (tid == (p & 255u)){
      knn_idx[(size_t)blk * K_ + r] = (int)p;
      float* np_ = neigh + ((size_t)blk * K_ + r) * 3;
      np_[0] = __fadd_rn(xb[p*3+0], -c0);
      np_[1] = __fadd_rn(xb[p*3+1], -c1);
      np_[2] = __fadd_rn(xb[p*3+2], -c2v);
      lmin = FINF; lp = 0xFFFFFFFFu;
#pragma unroll
      for (int j = 0; j < 32; j++){
        if ((unsigned int)(tid + j*256) == p) d[j] = FINF;
        if (d[j] < lmin){ lmin = d[j]; lp = (unsigned int)(tid + j*256); }
      }
    }
  }
}

// ---------------- fused group encoder (MFMA bf16): one block per (b,g) ----------------
__global__ __launch_bounds__(256, 2) void encoder_kernel(
    const float* __restrict__ neigh,
    const float* __restrict__ w1f, const float* __restrict__ b1f,
    const unsigned short* __restrict__ w2ph, const unsigned short* __restrict__ w2pl,
    const float* __restrict__ b2,
    const float* __restrict__ w3f, const float* __restrict__ b3f,
    const unsigned short* __restrict__ w3ph, const unsigned short* __restrict__ w3pl,
    const unsigned short* __restrict__ w4ph, const unsigned short* __restrict__ w4pl,
    const float* __restrict__ b4,
    float* __restrict__ tokens)
{
  __shared__ __align__(16) unsigned short sH1[64 * 136];  // h1 (64x128 bf16), reused as h3 chunk
  __shared__ __align__(16) unsigned short sH2[64 * 264];  // h2 (64x256 bf16)
  __shared__ float sGmax[256];
  __shared__ float sPartA[512];
  __shared__ float sNeigh[64][4];

  int tid  = threadIdx.x;
  int wave = tid >> 6, lane = tid & 63, quad = lane >> 4, lrow = lane & 15;
  size_t gid = blockIdx.x;

  if (tid < 192) sNeigh[tid / 3][tid % 3] = neigh[gid * 192 + tid];
  __syncthreads();

  // ---- phase 1: h1 = relu(bn(neigh @ w1)) -> bf16 LDS ----
  for (int e = tid; e < 8192; e += 256){
    int r = e >> 7, c = e & 127;
    float v = fmaf(sNeigh[r][2], w1f[256 + c], fmaf(sNeigh[r][1], w1f[128 + c], fmaf(sNeigh[r][0], w1f[c], b1f[c])));
    sH1[r * 136 + c] = f32_to_bf16(fmaxf(v, 0.0f));
  }
  __syncthreads();

  // ---- phase 2: h2 = h1 @ w2 + b2 (MFMA, hi/lo) ----
  {
    f32x4 acc[4][4];
    const f32x4 z = {0.f, 0.f, 0.f, 0.f};
#pragma unroll
    for (int mt = 0; mt < 4; mt++)
#pragma unroll
      for (int nl = 0; nl < 4; nl++) acc[mt][nl] = z;
#pragma unroll
    for (int ks = 0; ks < 4; ks++){
      bf16x8 af[4];
#pragma unroll
      for (int mt = 0; mt < 4; mt++)
        af[mt] = *(const bf16x8*)&sH1[(mt*16 + lrow)*136 + ks*32 + quad*8];
#pragma unroll
      for (int nl = 0; nl < 4; nl++){
        size_t bo = (((size_t)(wave*4 + nl)*4 + ks)*64 + lane)*8;
        bf16x8 bh = *(const bf16x8*)&w2ph[bo];
        bf16x8 bl = *(const bf16x8*)&w2pl[bo];
#pragma unroll
        for (int mt = 0; mt < 4; mt++){
          acc[mt][nl] = __builtin_amdgcn_mfma_f32_16x16x32_bf16(af[mt], bh, acc[mt][nl], 0, 0, 0);
          acc[mt][nl] = __builtin_amdgcn_mfma_f32_16x16x32_bf16(af[mt], bl, acc[mt][nl], 0, 0, 0);
        }
      }
    }
#pragma unroll
    for (int nl = 0; nl < 4; nl++){
      int col = wave*64 + nl*16 + lrow;
      float bias = b2[col];
#pragma unroll
      for (int mt = 0; mt < 4; mt++)
#pragma unroll
        for (int rg = 0; rg < 4; rg++)
          sH2[(mt*16 + quad*4 + rg)*264 + col] = f32_to_bf16(acc[mt][nl][rg] + bias);
    }
  }
  __syncthreads();

  // ---- phase 3: gmax = colmax(h2) ----
  {
    float mx = -3.4e38f;
#pragma unroll 8
    for (int r = 0; r < 64; r++) mx = fmaxf(mx, bf16_to_f32(sH2[r*264 + tid]));
    sGmax[tid] = mx;
  }
  __syncthreads();

  // ---- phase 4: partA = gmax @ w3f[0:256] (f32, coalesced) ----
#pragma unroll
  for (int half = 0; half < 2; half++){
    int c = tid + half * 256;
    float s = 0.0f;
#pragma unroll 8
    for (int k = 0; k < 256; k++) s = fmaf(sGmax[k], w3f[(size_t)k * 512 + c], s);
    sPartA[c] = s;
  }
  __syncthreads();

  // ---- phase 5: h3 (chunks of 128 cols) + h4 accumulation (MFMA, hi/lo) ----
  f32x4 acc4[4][4];
  {
    const f32x4 z = {0.f, 0.f, 0.f, 0.f};
#pragma unroll
    for (int mt = 0; mt < 4; mt++)
#pragma unroll
      for (int nl = 0; nl < 4; nl++) acc4[mt][nl] = z;
  }
  for (int cc = 0; cc < 4; cc++){
    f32x4 acc3[4][2];
    {
      const f32x4 z = {0.f, 0.f, 0.f, 0.f};
#pragma unroll
      for (int mt = 0; mt < 4; mt++){ acc3[mt][0] = z; acc3[mt][1] = z; }
    }
#pragma unroll
    for (int ks = 0; ks < 8; ks++){
      bf16x8 af[4];
#pragma unroll
      for (int mt = 0; mt < 4; mt++)
        af[mt] = *(const bf16x8*)&sH2[(mt*16 + lrow)*264 + ks*32 + quad*8];
#pragma unroll
      for (int nl = 0; nl < 2; nl++){
        int nt = cc*8 + wave*2 + nl;
        size_t bo = (((size_t)nt*8 + ks)*64 + lane)*8;
        bf16x8 bh = *(const bf16x8*)&w3ph[bo];
        bf16x8 bl = *(const bf16x8*)&w3pl[bo];
#pragma unroll
        for (int mt = 0; mt < 4; mt++){
          acc3[mt][nl] = __builtin_amdgcn_mfma_f32_16x16x32_bf16(af[mt], bh, acc3[mt][nl], 0, 0, 0);
          acc3[mt][nl] = __builtin_amdgcn_mfma_f32_16x16x32_bf16(af[mt], bl, acc3[mt][nl], 0, 0, 0);
        }
      }
    }
    __syncthreads(); // previous chunk's h4 reads of sH1 are done
#pragma unroll
    for (int nl = 0; nl < 2; nl++){
      int cl = wave*32 + nl*16 + lrow;
      int c  = cc*128 + cl;
      float pb = sPartA[c] + b3f[c];
#pragma unroll
      for (int mt = 0; mt < 4; mt++)
#pragma unroll
        for (int rg = 0; rg < 4; rg++)
          sH1[(mt*16 + quad*4 + rg)*136 + cl] = f32_to_bf16(fmaxf(acc3[mt][nl][rg] + pb, 0.0f));
    }
    __syncthreads();
#pragma unroll
    for (int ks = 0; ks < 4; ks++){
      bf16x8 af[4];
#pragma unroll
      for (int mt = 0; mt < 4; mt++)
        af[mt] = *(const bf16x8*)&sH1[(mt*16 + lrow)*136 + ks*32 + quad*8];
#pragma unroll
      for (int nl = 0; nl < 4; nl++){
        int nt = wave*4 + nl;
        size_t bo = (((size_t)nt*16 + cc*4 + ks)*64 + lane)*8;
        bf16x8 bh = *(const bf16x8*)&w4ph[bo];
        bf16x8 bl = *(const bf16x8*)&w4pl[bo];
#pragma unroll
        for (int mt = 0; mt < 4; mt++){
          acc4[mt][nl] = __builtin_amdgcn_mfma_f32_16x16x32_bf16(af[mt], bh, acc4[mt][nl], 0, 0, 0);
          acc4[mt][nl] = __builtin_amdgcn_mfma_f32_16x16x32_bf16(af[mt], bl, acc4[mt][nl], 0, 0, 0);
        }
      }
    }
  }

  // ---- phase 6: tokens = colmax(h4) + b4 ----
#pragma unroll
  for (int nl = 0; nl < 4; nl++){
    float mx = -3.4e38f;
#pragma unroll
    for (int mt = 0; mt < 4; mt++)
#pragma unroll
      for (int rg = 0; rg < 4; rg++) mx = fmaxf(mx, acc4[mt][nl][rg]);
    mx = fmaxf(mx, __shfl_xor(mx, 16));
    mx = fmaxf(mx, __shfl_xor(mx, 32));
    if (quad == 0){
      int col = wave*64 + nl*16 + lrow;
      tokens[gid * 256 + col] = mx + b4[col];
    }
  }
}

// ---------------- pos embed + assemble xt/pt ----------------
__global__ __launch_bounds__(128) void pos_token_kernel(
    const float* __restrict__ centers, const float* __restrict__ tokens,
    const float* __restrict__ cls_token, const float* __restrict__ cls_pos,
    const float* __restrict__ pw1, const float* __restrict__ pb1,
    const float* __restrict__ pw2, const float* __restrict__ pb2,
    float* __restrict__ xt, float* __restrict__ pt)
{
  int row = blockIdx.x;
  int b = row / 257, n = row - b * 257;
  int tid = threadIdx.x;
  size_t ro = (size_t)row * 256;
  if (n == 0){
    xt[ro + tid] = cls_token[tid]; xt[ro + 128 + tid] = cls_token[128 + tid];
    pt[ro + tid] = cls_pos[tid];   pt[ro + 128 + tid] = cls_pos[128 + tid];
    return;
  }
  int g = n - 1;
  const float* c = centers + ((size_t)b * 256 + g) * 3;
  __shared__ float hS[128];
  float h = fmaf(c[2], pw1[256 + tid], fmaf(c[1], pw1[128 + tid], fmaf(c[0], pw1[tid], pb1[tid])));
  hS[tid] = gelu_exact(h);
  __syncthreads();
  const float* tok = tokens + ((size_t)b * 256 + g) * 256;
#pragma unroll
  for (int half = 0; half < 2; half++){
    int j = tid + half * 128;
    float s = pb2[j];
#pragma unroll 4
    for (int k = 0; k < 128; k++) s = fmaf(hS[k], pw2[(size_t)k * 256 + j], s);
    pt[ro + j] = s;
    xt[ro + j] = tok[j];
  }
}

// ---------------- add + layernorm (row of 256) ----------------
__global__ __launch_bounds__(256) void add_ln_kernel(const float* __restrict__ A, const float* __restrict__ Badd,
    float* __restrict__ xi_out, float* __restrict__ ln_out,
    const float* __restrict__ g, const float* __restrict__ be)
{
  __shared__ float red[4];
  int row = blockIdx.x, c = threadIdx.x;
  size_t off = (size_t)row * 256 + c;
  float v = A[off];
  if (Badd) v += Badd[off];
  if (xi_out) xi_out[off] = v;
  float s = v;
#pragma unroll
  for (int o = 32; o; o >>= 1) s += __shfl_down(s, o);
  if ((threadIdx.x & 63) == 0) red[threadIdx.x >> 6] = s;
  __syncthreads();
  float m = (red[0] + red[1] + red[2] + red[3]) * (1.0f / 256.0f);
  __syncthreads();
  float d = v - m;
  float s2 = d * d;
#pragma unroll
  for (int o = 32; o; o >>= 1) s2 += __shfl_down(s2, o);
  if ((threadIdx.x & 63) == 0) red[threadIdx.x >> 6] = s2;
  __syncthreads();
  float var = (red[0] + red[1] + red[2] + red[3]) * (1.0f / 256.0f);
  ln_out[off] = d / sqrtf(var + EPS_) * g[c] + be[c];
}

// ---------------- generic tiled f32 GEMM (64x64 tile, 4x4/thread) ----------------
template<int ACT>
__global__ __launch_bounds__(256) void gemm_kernel(
    const float* __restrict__ A, const float* __restrict__ W, const float* __restrict__ bias,
    const float* __restrict__ res, float* __restrict__ C, int M, int K, int N)
{
  __shared__ float As[16][68];
  __shared__ float Ws[16][68];
  int row0 = blockIdx.x * 64, col0 = blockIdx.y * 64;
  int tid = threadIdx.x;
  int tr = tid >> 4, tc = tid & 15;
  int ar = tid >> 2, ac = (tid & 3) * 4;
  int wr = tid >> 4, wc = (tid & 15) * 4;
  float acc[4][4];
#pragma unroll
  for (int i = 0; i < 4; i++)
#pragma unroll
    for (int j = 0; j < 4; j++) acc[i][j] = 0.0f;
  for (int k0 = 0; k0 < K; k0 += 16){
    float4 av = make_float4(0.f, 0.f, 0.f, 0.f);
    int arow = row0 + ar;
    if (arow < M) av = *(const float4*)(A + (size_t)arow * K + k0 + ac);
    As[ac+0][ar] = av.x; As[ac+1][ar] = av.y; As[ac+2][ar] = av.z; As[ac+3][ar] = av.w;
    *(float4*)(&Ws[wr][wc]) = *(const float4*)(W + (size_t)(k0 + wr) * N + col0 + wc);
    __syncthreads();
#pragma unroll
    for (int kk = 0; kk < 16; kk++){
      float a0 = As[kk][tr*4+0], a1 = As[kk][tr*4+1], a2 = As[kk][tr*4+2], a3 = As[kk][tr*4+3];
      float4 bv = *(float4*)(&Ws[kk][tc*4]);
      acc[0][0]=fmaf(a0,bv.x,acc[0][0]); acc[0][1]=fmaf(a0,bv.y,acc[0][1]); acc[0][2]=fmaf(a0,bv.z,acc[0][2]); acc[0][3]=fmaf(a0,bv.w,acc[0][3]);
      acc[1][0]=fmaf(a1,bv.x,acc[1][0]); acc[1][1]=fmaf(a1,bv.y,acc[1][1]); acc[1][2]=fmaf(a1,bv.z,acc[1][2]); acc[1][3]=fmaf(a1,bv.w,acc[1][3]);
      acc[2][0]=fmaf(a2,bv.x,acc[2][0]); acc[2][1]=fmaf(a2,bv.y,acc[2][1]); acc[2][2]=fmaf(a2,bv.z,acc[2][2]); acc[2][3]=fmaf(a2,bv.w,acc[2][3]);
      acc[3][0]=fmaf(a3,bv.x,acc[3][0]); acc[3][1]=fmaf(a3,bv.y,acc[3][1]); acc[3][2]=fmaf(a3,bv.z,acc[3][2]); acc[3][3]=fmaf(a3,bv.w,acc[3][3]);
    }
    __syncthreads();
  }
#pragma unroll
  for (int i = 0; i < 4; i++){
    int r = row0 + tr * 4 + i;
    if (r < M){
#pragma unroll
      for (int j = 0; j < 4; j++){
        int c = col0 + tc * 4 + j;
        float v = acc[i][j];
        if (bias) v += bias[c];
        if (ACT == 1) v = gelu_exact(v);
        if (res) v += res[(size_t)r * N + c];
        C[(size_t)r * N + c] = v;
      }
    }
  }
}

// ---------------- attention: one block per (b,h), flash-style ----------------
__global__ __launch_bounds__(320) void attn_kernel(const float* __restrict__ qkv, float* __restrict__ obuf)
{
  int bh = blockIdx.x;
  int b = bh >> 3, h = bh & 7;
  __shared__ float kS[128][33];
  __shared__ float vS[128][33];
  const float* qb = qkv + (size_t)b * 257 * 768;
  int tid = threadIdx.x;
  float q[32], o[32];
  float mrun = -3.4e38f, l = 0.0f;
  if (tid < 257){
    const float* qr = qb + (size_t)tid * 768 + h * 32;
#pragma unroll
    for (int j = 0; j < 32; j++){ q[j] = qr[j]; o[j] = 0.0f; }
  }
  const float scale = 0.17677669529663687f;
  for (int m0 = 0; m0 < 257; m0 += 128){
    int cnt = min(128, 257 - m0);
    for (int e = tid; e < cnt * 32; e += 320){
      int mm = e >> 5, j = e & 31;
      const float* rowp = qb + (size_t)(m0 + mm) * 768 + h * 32;
      kS[mm][j] = rowp[256 + j];
      vS[mm][j] = rowp[512 + j];
    }
    __syncthreads();
    if (tid < 257){
      for (int mm = 0; mm < cnt; mm++){
        float s = 0.0f;
#pragma unroll
        for (int j = 0; j < 32; j++) s = fmaf(q[j], kS[mm][j], s);
        s *= scale;
        float nm = fmaxf(mrun, s);
        float alpha = expf(mrun - nm);
        float p = expf(s - nm);
        l = fmaf(l, alpha, p);
#pragma unroll
        for (int j = 0; j < 32; j++) o[j] = fmaf(p, vS[mm][j], o[j] * alpha);
        mrun = nm;
      }
    }
    __syncthreads();
  }
  if (tid < 257){
    float inv = 1.0f / l;
    float* orow = obuf + (size_t)(b * 257 + tid) * 256 + h * 32;
#pragma unroll
    for (int j = 0; j < 32; j++) orow[j] = o[j] * inv;
  }
}

// ---------------- head MLP + scatter: one block per (b,g) ----------------
// concat = [gfeat(g) broadcast | neigh] -> the gfeat part of h is IDENTICAL for
// all 64 rows: compute it once per block, then per-row add the 3-dim tail.
__global__ __launch_bounds__(256) void head_kernel(
    const float* __restrict__ gfeat, const float* __restrict__ neigh, const int* __restrict__ knn_idx,
    const float* __restrict__ w1, const float* __restrict__ b1,
    const float* __restrict__ w2, const float* __restrict__ b2,
    float* __restrict__ sums, float* __restrict__ cnts)
{
  int blk = blockIdx.x, b = blk >> 8;
  __shared__ float xS[256];
  __shared__ float nS[64][4];
  __shared__ float partH[2][128];
  __shared__ float sharedH[128];
  __shared__ float w2S[128];
  __shared__ float wtail[3][128];
  int tid = threadIdx.x;
  xS[tid] = gfeat[((size_t)b * 257 + 1 + (blk & 255)) * 256 + tid];
  if (tid < 192) nS[tid / 3][tid % 3] = neigh[(size_t)blk * 192 + tid];
  if (tid < 128){
    w2S[tid] = w2[tid];
    wtail[0][tid] = w1[256 * 128 + tid];
    wtail[1][tid] = w1[257 * 128 + tid];
    wtail[2][tid] = w1[258 * 128 + tid];
  }
  __syncthreads();
  {
    int half = tid >> 7, j = tid & 127;
    float s = 0.0f;
#pragma unroll 8
    for (int k = 0; k < 128; k++) s = fmaf(xS[half * 128 + k], w1[(size_t)(half * 128 + k) * 128 + j], s);
    partH[half][j] = s;
  }
  __syncthreads();
  if (tid < 128) sharedH[tid] = partH[0][tid] + partH[1][tid] + b1[tid];
  __syncthreads();
  int r = tid >> 2, q = tid & 3;
  float n0 = nS[r][0], n1 = nS[r][1], n2 = nS[r][2];
  float s = 0.0f;
#pragma unroll
  for (int j0 = 0; j0 < 32; j0++){
    int j = q * 32 + j0;
    float h = fmaf(n2, wtail[2][j], fmaf(n1, wtail[1][j], fmaf(n0, wtail[0][j], sharedH[j])));
    s = fmaf(fmaxf(h, 0.0f), w2S[j], s);
  }
  s += __shfl_xor(s, 1);
  s += __shfl_xor(s, 2);
  if (q == 0){
    float lg = s + b2[0];
    int p = knn_idx[(size_t)blk * K_ + r];
    atomicAdd(&sums[(size_t)b * N_ + p], lg);
    atomicAdd(&cnts[(size_t)b * N_ + p], 1.0f);
  }
}

__global__ void finalize_kernel(const float* __restrict__ sums, const float* __restrict__ cnts, float* __restrict__ out)
{
  int i = blockIdx.x * 256 + threadIdx.x;
  out[i] = sums[i] / fmaxf(cnts[i], 1.0f);
}

extern "C" void kernel_launch(void* const* d_in, const int* in_sizes, int n_in,
                              void* d_out, int out_size, void* d_ws, size_t ws_size,
                              hipStream_t stream)
{
  (void)in_sizes; (void)n_in; (void)out_size; (void)ws_size;
  const float* x        = (const float*)d_in[0];
  const float* enc_w1   = (const float*)d_in[1];
  const float* enc_b1   = (const float*)d_in[2];
  const float* enc_bn1g = (const float*)d_in[3];
  const float* enc_bn1b = (const float*)d_in[4];
  const float* enc_w2   = (const float*)d_in[5];
  const float* enc_b2   = (const float*)d_in[6];
  const float* enc_w3   = (const float*)d_in[7];
  const float* enc_b3   = (const float*)d_in[8];
  const float* enc_bn2g = (const float*)d_in[9];
  const float* enc_bn2b = (const float*)d_in[10];
  const float* enc_w4   = (const float*)d_in[11];
  const float* enc_b4   = (const float*)d_in[12];
  const float* cls_tok  = (const float*)d_in[13];
  const float* cls_pos  = (const float*)d_in[14];
  const float* pos_w1   = (const float*)d_in[15];
  const float* pos_b1   = (const float*)d_in[16];
  const float* pos_w2   = (const float*)d_in[17];
  const float* pos_b2   = (const float*)d_in[18];
  const float* ln1_g    = (const float*)d_in[19];
  const float* ln1_b    = (const float*)d_in[20];
  const float* qkv_w    = (const float*)d_in[21];
  const float* proj_w   = (const float*)d_in[22];
  const float* proj_b   = (const float*)d_in[23];
  const float* ln2_g    = (const float*)d_in[24];
  const float* ln2_b    = (const float*)d_in[25];
  const float* fc1_w    = (const float*)d_in[26];
  const float* fc1_b    = (const float*)d_in[27];
  const float* fc2_w    = (const float*)d_in[28];
  const float* fc2_b    = (const float*)d_in[29];
  const float* norm_g   = (const float*)d_in[30];
  const float* norm_b   = (const float*)d_in[31];
  const float* head_w1  = (const float*)d_in[32];
  const float* head_b1  = (const float*)d_in[33];
  const float* head_w2  = (const float*)d_in[34];
  const float* head_b2  = (const float*)d_in[35];

  float* ws = (float*)d_ws;
  size_t off = 0;
  auto alloc = [&](size_t n)->float*{ float* p = ws + off; off += (n + 63) & ~(size_t)63; return p; };

  float* centers = alloc((size_t)B_ * G_ * 3);
  float* w1f     = alloc(384);
  float* b1f     = alloc(128);
  float* w3f     = alloc(512 * 512);
  float* b3f     = alloc(512);
  unsigned short* w2ph = (unsigned short*)alloc(16384);
  unsigned short* w2pl = (unsigned short*)alloc(16384);
  unsigned short* w3ph = (unsigned short*)alloc(65536);
  unsigned short* w3pl = (unsigned short*)alloc(65536);
  unsigned short* w4ph = (unsigned short*)alloc(65536);
  unsigned short* w4pl = (unsigned short*)alloc(65536);
  float* tokens  = alloc((size_t)B_ * G_ * D_);
  float* neigh   = alloc((size_t)B_ * G_ * K_ * 3);
  int*   knn_idx = (int*)alloc((size_t)B_ * G_ * K_);
  float* pt      = alloc((size_t)B_ * 257 * D_);
  float* xt      = alloc((size_t)B_ * 257 * D_);
  float* xi      = alloc((size_t)B_ * 257 * D_);
  float* lnbuf   = alloc((size_t)B_ * 257 * D_);
  float* obuf    = alloc((size_t)B_ * 257 * D_);
  float* bigbuf  = alloc((size_t)B_ * 257 * HID_);
  float* gfeat   = alloc((size_t)B_ * 257 * D_);
  float* sums    = alloc((size_t)B_ * N_);
  float* cnts    = alloc((size_t)B_ * N_);

  hipMemsetAsync(sums, 0, (size_t)2 * B_ * N_ * sizeof(float), stream);

  fold_kernel<<<1024, 256, 0, stream>>>(enc_w1, enc_b1, enc_bn1g, enc_bn1b,
                                        enc_w3, enc_b3, enc_bn2g, enc_bn2b,
                                        w1f, b1f, w3f, b3f);
  pack_w2_kernel<<<128, 256, 0, stream>>>(enc_w2, w2ph, w2pl);
  pack_w3_kernel<<<512, 256, 0, stream>>>(w3f, w3ph, w3pl);
  pack_w4_kernel<<<512, 256, 0, stream>>>(enc_w4, w4ph, w4pl);

  fps_kernel<<<B_, 1024, 0, stream>>>(x, centers);
  knn_kernel<<<B_ * G_, 256, 0, stream>>>(x, centers, knn_idx, neigh);
  encoder_kernel<<<B_ * G_, 256, 0, stream>>>(neigh, w1f, b1f, w2ph, w2pl, enc_b2,
                                              w3f, b3f, w3ph, w3pl, w4ph, w4pl, enc_b4, tokens);
  pos_token_kernel<<<B_ * 257, 128, 0, stream>>>(centers, tokens, cls_tok, cls_pos,
                                                 pos_w1, pos_b1, pos_w2, pos_b2, xt, pt);
  const int M = B_ * 257; // 4112
  for (int l = 0; l < 4; l++){
    add_ln_kernel<<<M, 256, 0, stream>>>(xt, pt, xi, lnbuf, ln1_g + l*256, ln1_b + l*256);
    gemm_kernel<0><<<dim3(65, 12), 256, 0, stream>>>(lnbuf, qkv_w + (size_t)l*256*768, nullptr, nullptr, bigbuf, M, 256, 768);
    attn_kernel<<<B_ * 8, 320, 0, stream>>>(bigbuf, obuf);
    gemm_kernel<0><<<dim3(65, 4), 256, 0, stream>>>(obuf, proj_w + (size_t)l*256*256, proj_b + l*256, xi, xi, M, 256, 256);
    add_ln_kernel<<<M, 256, 0, stream>>>(xi, nullptr, nullptr, lnbuf, ln2_g + l*256, ln2_b + l*256);
    gemm_kernel<1><<<dim3(65, 16), 256, 0, stream>>>(lnbuf, fc1_w + (size_t)l*256*1024, fc1_b + l*1024, nullptr, bigbuf, M, 256, 1024);
    gemm_kernel<0><<<dim3(65, 4), 256, 0, stream>>>(bigbuf, fc2_w + (size_t)l*1024*256, fc2_b + l*256, xi, xt, M, 1024, 256);
  }
  add_ln_kernel<<<M, 256, 0, stream>>>(xt, nullptr, nullptr, gfeat, norm_g, norm_b);
  head_kernel<<<B_ * G_, 256, 0, stream>>>(gfeat, neigh, knn_idx, head_w1, head_b1, head_w2, head_b2, sums, cnts);
  finalize_kernel<<<(B_ * N_) / 256, 256, 0, stream>>>(sums, cnts, (float*)d_out);
}